// Round 5
// baseline (330.870 us; speedup 1.0000x reference)
//
#include <hip/hip_runtime.h>

#define G_GROUPS 512
#define CNT      8192
#define S_PAIRS  8192
#define BLOCK    1024
#define WAVES    (BLOCK / 64)        // 16
#define PPT      (S_PAIRS / BLOCK)   // 8 pairs per thread per group
#define GPB      2                   // groups per block (persistent)
#define NWG      (G_GROUPS / GPB)    // 256 blocks = 1 per CU

// Load one CA row (16 B at record byte offset 36r+12; 4B-aligned).
#define LOADCA(dst, src, rec)                                         \
    __builtin_memcpy(&(dst), (src) + (size_t)(rec) * 9 + 3, 16)

// 8 reg-staged CA loads, named scalars (spill-proof; round-2 post-mortem).
#define LOAD8(p, SRC, GB)                                             \
    float4 p##0, p##1, p##2, p##3, p##4, p##5, p##6, p##7;            \
    LOADCA(p##0, SRC, (GB) + tid + 0 * BLOCK);                        \
    LOADCA(p##1, SRC, (GB) + tid + 1 * BLOCK);                        \
    LOADCA(p##2, SRC, (GB) + tid + 2 * BLOCK);                        \
    LOADCA(p##3, SRC, (GB) + tid + 3 * BLOCK);                        \
    LOADCA(p##4, SRC, (GB) + tid + 4 * BLOCK);                        \
    LOADCA(p##5, SRC, (GB) + tid + 5 * BLOCK);                        \
    LOADCA(p##6, SRC, (GB) + tid + 6 * BLOCK);                        \
    LOADCA(p##7, SRC, (GB) + tid + 7 * BLOCK);

// Publish 8 staged rows (ds_write_b128; implicit per-reg vmcnt waits).
#define WRITE8(p)                                                     \
    tab4[tid + 0 * BLOCK] = p##0;  tab4[tid + 1 * BLOCK] = p##1;      \
    tab4[tid + 2 * BLOCK] = p##2;  tab4[tid + 3 * BLOCK] = p##3;      \
    tab4[tid + 4 * BLOCK] = p##4;  tab4[tid + 5 * BLOCK] = p##5;      \
    tab4[tid + 6 * BLOCK] = p##6;  tab4[tid + 7 * BLOCK] = p##7;

#define GATH_DIN(LI, RI)                                              \
    _Pragma("unroll")                                                 \
    for (int i = 0; i < PPT; ++i) {                                   \
        const float4 L = tab4[LI[i]];                                 \
        const float4 R = tab4[RI[i]];                                 \
        const float dx = L.x - R.x, dy = L.y - R.y, dz = L.z - R.z;   \
        din[i] = sqrtf(dx * dx + dy * dy + dz * dz);                  \
    }

#define GATH_DTG(LI, RI)                                              \
    _Pragma("unroll")                                                 \
    for (int i = 0; i < PPT; ++i) {                                   \
        const float4 L = tab4[LI[i]];                                 \
        const float4 R = tab4[RI[i]];                                 \
        const float dx = L.x - R.x, dy = L.y - R.y, dz = L.z - R.z;   \
        const float d  = din[i] - sqrtf(dx * dx + dy * dy + dz * dz); \
        acc += d * d;                                                 \
    }

// Barrier WITHOUT vmcnt drain: publishes this wave's LDS ops, then block
// barrier. The "memory" clobbers also pin global loads into their phase
// window (no hoist/sink across) without forcing a wait on their data.
__device__ __forceinline__ void fencebar() {
    asm volatile("s_waitcnt lgkmcnt(0)" ::: "memory");
    __builtin_amdgcn_s_barrier();
    asm volatile("" ::: "memory");
}

__global__ __launch_bounds__(BLOCK, 4) void rgn_loss_kernel(
    const float* __restrict__ inputs,
    const float* __restrict__ target,
    const int*   __restrict__ left,
    const int*   __restrict__ right,
    float*       __restrict__ out)
{
    __shared__ float4 tab4[CNT];          // 128 KiB, one tensor at a time
    __shared__ float  red[WAVES];

    const int tid = threadIdx.x;
    const int lane = tid & 63;
    const int wid  = tid >> 6;

    const int gA = blockIdx.x * GPB;      // this block's two groups
    const int gB = gA + 1;
    const int baseA = gA * CNT;
    const int baseB = gB * CNT;

    float din[PPT];
    float acc = 0.0f;

    // ================= Group A =================
    // Pair indices + input CA rows (concurrent streams).
    int ali[PPT], ari[PPT];
    {
        const size_t pb = (size_t)gA * S_PAIRS;
        #pragma unroll
        for (int i = 0; i < PPT; ++i) {
            ali[i] = left [pb + tid + i * BLOCK] - baseA;
            ari[i] = right[pb + tid + i * BLOCK] - baseA;
        }
    }
    LOAD8(av, inputs, baseA)
    WRITE8(av)
    fencebar();                            // A-input table published

    LOAD8(at, target, baseA)               // A-target streams under d_in gather
    GATH_DIN(ali, ari)
    fencebar();                            // gather reads done before overwrite

    WRITE8(at)                             // waits only A-target regs
    fencebar();                            // A-target table published

    // B prefetch streams under A's d_tg gather.
    LOAD8(bv, inputs, baseB)
    int bli[PPT], bri[PPT];
    {
        const size_t pb = (size_t)gB * S_PAIRS;
        #pragma unroll
        for (int i = 0; i < PPT; ++i) {
            bli[i] = left [pb + tid + i * BLOCK] - baseB;
            bri[i] = right[pb + tid + i * BLOCK] - baseB;
        }
    }
    GATH_DTG(ali, ari)
    fencebar();                            // gather reads done before overwrite

    // ================= Group B =================
    WRITE8(bv)
    fencebar();                            // B-input table published

    LOAD8(bt, target, baseB)               // B-target streams under d_in gather
    GATH_DIN(bli, bri)
    fencebar();

    WRITE8(bt)
    fencebar();                            // B-target table published

    GATH_DTG(bli, bri)                     // exposed tail (~3 µs) — nothing left

    // ---- Block reduction -> one atomic (256 total) ----
    #pragma unroll
    for (int off = 32; off > 0; off >>= 1)
        acc += __shfl_down(acc, off);
    if (lane == 0) red[wid] = acc;
    __syncthreads();
    if (wid == 0) {
        float v = (lane < WAVES) ? red[lane] : 0.0f;
        #pragma unroll
        for (int off = 8; off > 0; off >>= 1)
            v += __shfl_down(v, off);
        if (lane == 0)
            atomicAdd(out, v * (1.0f / ((float)G_GROUPS * (float)S_PAIRS)));
    }
}

extern "C" void kernel_launch(void* const* d_in, const int* in_sizes, int n_in,
                              void* d_out, int out_size, void* d_ws, size_t ws_size,
                              hipStream_t stream) {
    const float* inputs = (const float*)d_in[0];
    const float* target = (const float*)d_in[1];
    const int*   left   = (const int*)d_in[2];
    const int*   right  = (const int*)d_in[3];
    float*       out    = (float*)d_out;

    hipMemsetAsync(out, 0, sizeof(float), stream);   // graph-capture safe
    rgn_loss_kernel<<<NWG, BLOCK, 0, stream>>>(inputs, target, left, right, out);
}